// Round 1
// baseline (481.085 us; speedup 1.0000x reference)
//
#include <hip/hip_runtime.h>

#define PP 16
#define BB 64
#define TT 512
#define NN 48

// ---------- helpers ----------

__device__ __forceinline__ float rl(float v, int i) {
    return __builtin_bit_cast(float, __builtin_amdgcn_readlane(__builtin_bit_cast(int, v), i));
}
__device__ __forceinline__ float rfl(float v) {
    return __builtin_bit_cast(float, __builtin_amdgcn_readfirstlane(__builtin_bit_cast(int, v)));
}
__device__ __forceinline__ float wsum(float v) {
#pragma unroll
    for (int k = 32; k >= 1; k >>= 1) v += __shfl_xor(v, k, 64);
    return v;
}

// lane c owns column c of trans; E[i] = exp(trans[i][c] - s_c), s_c = max_i trans[i][c]
__device__ __forceinline__ float init_E(const float* s_trans, int c, float* E) {
    float sj = -1e30f;
#pragma unroll
    for (int i = 0; i < NN; ++i) sj = fmaxf(sj, s_trans[i * NN + c]);
#pragma unroll
    for (int i = 0; i < NN; ++i) E[i] = __expf(s_trans[i * NN + c] - sj);
    return sj;
}

// one CRF forward step: alpha'_j = s_j + log(sum_i exp(alpha_i - delta) E_ij) + em_j ; C += delta
__device__ __forceinline__ void crf_step(float& d, float& C, float em,
                                         const float* __restrict__ E, float sj) {
    float delta = rfl(d);
    float u = __expf(d - delta);
    float a0 = 0.f, a1 = 0.f, a2 = 0.f, a3 = 0.f;
#pragma unroll
    for (int i = 0; i < NN; i += 4) {
        a0 = fmaf(rl(u, i + 0), E[i + 0], a0);
        a1 = fmaf(rl(u, i + 1), E[i + 1], a1);
        a2 = fmaf(rl(u, i + 2), E[i + 2], a2);
        a3 = fmaf(rl(u, i + 3), E[i + 3], a3);
    }
    float v = (a0 + a1) + (a2 + a3);
    d = sj + __logf(v) + em;
    C += delta;
}

__device__ __forceinline__ float finish_logden(float d, float C, int lane) {
    float delta = rfl(d);
    float ex = (lane < NN) ? __expf(d - delta) : 0.f;
    float S = wsum(ex);
    return C + delta + __logf(S);
}

// ---------- kernels ----------

__global__ void zero_out(float* out) {
    if (threadIdx.x < 3) out[threadIdx.x] = 0.f;
}

// T direction: 1024 sequences (p,b), length T-p, one wave per sequence.
__global__ __launch_bounds__(256) void crf_T(const float* __restrict__ logits,
                                             const float* __restrict__ trans,
                                             const int* __restrict__ tags,
                                             float* __restrict__ out) {
    __shared__ float s_trans[NN * NN];
    __shared__ float s_acc;
    int tid = threadIdx.x;
    if (tid == 0) s_acc = 0.f;
    for (int i = tid; i < NN * NN; i += 256) s_trans[i] = trans[i];
    __syncthreads();

    int lane = tid & 63, widx = tid >> 6;
    int s = blockIdx.x * 4 + widx;  // 0..1023 == p*64+b
    int p = s >> 6;
    int c = (lane < NN) ? lane : (NN - 1);
    float E[NN];
    float sj = init_E(s_trans, c, E);

    int L = TT - p;
    const float* lg = logits + (size_t)s * TT * NN;
    float d = lg[c];
    float C = 0.f;
    float em_next = lg[NN + c];
    for (int t = 1; t < L; ++t) {
        float em = em_next;
        em_next = lg[(size_t)(t + 1) * NN + c];  // prefetch (safe over-read inside buffer)
        crf_step(d, C, em, E, sj);
    }
    float log_den = finish_logden(d, C, lane);

    // numerator score
    const int* tg = tags + (size_t)s * TT;
    float sc = 0.f;
    for (int t0 = 0; t0 < L; t0 += 64) {
        int t = t0 + lane;
        if (t < L) {
            int tag = tg[t];
            sc += lg[(size_t)t * NN + tag];
            if (t >= 1) sc += s_trans[tg[t - 1] * NN + tag];
        }
    }
    sc = wsum(sc);
    if (lane == 0) atomicAdd(&s_acc, log_den - sc);
    __syncthreads();
    if (tid == 0) atomicAdd(&out[0], s_acc);
}

// L direction: 32768 sequences (t,b), length min(T-t,16), element p at logits[p,b,t].
__global__ __launch_bounds__(256) void crf_L(const float* __restrict__ logits,
                                             const float* __restrict__ trans,
                                             const int* __restrict__ tags,
                                             float* __restrict__ out) {
    __shared__ float s_trans[NN * NN];
    __shared__ float s_acc;
    int tid = threadIdx.x;
    if (tid == 0) s_acc = 0.f;
    for (int i = tid; i < NN * NN; i += 256) s_trans[i] = trans[i];
    __syncthreads();

    int lane = tid & 63, widx = tid >> 6;
    int wgid = blockIdx.x * 4 + widx;  // 0..8191
    int c = (lane < NN) ? lane : (NN - 1);
    float E[NN];
    float sj = init_E(s_trans, c, E);

    const int SP = BB * TT;        // p-stride in tags
    const int SPN = BB * TT * NN;  // p-stride in logits
    float tot = 0.f;
#pragma unroll
    for (int k = 0; k < 4; ++k) {
        int sq = wgid + k * 8192;  // 0..32767 == t*64+b
        int t = sq >> 6, b = sq & 63;
        int Lh = min(TT - t, PP);
        const float* base = logits + (size_t)(b * TT + t) * NN;
        float d = base[c];
        float C = 0.f;
        for (int ps = 1; ps < Lh; ++ps) {
            float em = base[(size_t)ps * SPN + c];
            crf_step(d, C, em, E, sj);
        }
        float log_den = finish_logden(d, C, lane);

        float sc = 0.f;
        int tagv = 0;
        if (lane < Lh) tagv = tags[lane * SP + b * TT + t];
        int tprev = __shfl_up(tagv, 1, 64);
        if (lane < Lh) {
            sc += logits[(size_t)lane * SPN + (size_t)(b * TT + t) * NN + tagv];
            if (lane >= 1) sc += s_trans[tprev * NN + tagv];
        }
        sc = wsum(sc);
        if (lane == 0) tot += log_den - sc;
    }
    if (lane == 0) atomicAdd(&s_acc, tot);
    __syncthreads();
    if (tid == 0) atomicAdd(&out[1], s_acc);
}

// R direction: 32768 sequences (t,b), length min(t+1,16), element p at logits[p,b,t-p].
__global__ __launch_bounds__(256) void crf_R(const float* __restrict__ logits,
                                             const float* __restrict__ trans,
                                             const int* __restrict__ tags,
                                             float* __restrict__ out) {
    __shared__ float s_trans[NN * NN];
    __shared__ float s_acc;
    int tid = threadIdx.x;
    if (tid == 0) s_acc = 0.f;
    for (int i = tid; i < NN * NN; i += 256) s_trans[i] = trans[i];
    __syncthreads();

    int lane = tid & 63, widx = tid >> 6;
    int wgid = blockIdx.x * 4 + widx;  // 0..8191
    int c = (lane < NN) ? lane : (NN - 1);
    float E[NN];
    float sj = init_E(s_trans, c, E);

    const int SP = BB * TT;
    const int SPN = BB * TT * NN;
    const int SR = SPN - NN;  // p-stride for diagonal elements in logits
    float tot = 0.f;
#pragma unroll
    for (int k = 0; k < 4; ++k) {
        int sq = wgid + k * 8192;
        int t = sq >> 6, b = sq & 63;
        int Lh = min(t + 1, PP);
        const float* base = logits + (size_t)(b * TT + t) * NN;
        float d = base[c];
        float C = 0.f;
        for (int ps = 1; ps < Lh; ++ps) {
            float em = base[(size_t)ps * SR + c];
            crf_step(d, C, em, E, sj);
        }
        float log_den = finish_logden(d, C, lane);

        float sc = 0.f;
        int tagv = 0;
        if (lane < Lh) tagv = tags[lane * (SP - 1) + b * TT + t];  // tags[p, b, t-p]
        int tprev = __shfl_up(tagv, 1, 64);
        if (lane < Lh) {
            sc += base[(size_t)lane * SR + tagv];
            if (lane >= 1) sc += s_trans[tprev * NN + tagv];
        }
        sc = wsum(sc);
        if (lane == 0) tot += log_den - sc;
    }
    if (lane == 0) atomicAdd(&s_acc, tot);
    __syncthreads();
    if (tid == 0) atomicAdd(&out[2], s_acc);
}

// ---------- launch ----------

extern "C" void kernel_launch(void* const* d_in, const int* in_sizes, int n_in,
                              void* d_out, int out_size, void* d_ws, size_t ws_size,
                              hipStream_t stream) {
    const float* logits = (const float*)d_in[0];
    const float* trans_T = (const float*)d_in[1];
    const float* trans_L = (const float*)d_in[2];
    const float* trans_R = (const float*)d_in[3];
    const int* tags = (const int*)d_in[4];
    float* out = (float*)d_out;

    hipLaunchKernelGGL(zero_out, dim3(1), dim3(64), 0, stream, out);
    hipLaunchKernelGGL(crf_L, dim3(2048), dim3(256), 0, stream, logits, trans_L, tags, out);
    hipLaunchKernelGGL(crf_R, dim3(2048), dim3(256), 0, stream, logits, trans_R, tags, out);
    hipLaunchKernelGGL(crf_T, dim3(256), dim3(256), 0, stream, logits, trans_T, tags, out);
}

// Round 2
// 388.197 us; speedup vs baseline: 1.2393x; 1.2393x over previous
//
#include <hip/hip_runtime.h>

#define PP 16
#define BB 64
#define TT 512
#define NN 48

// ---------- helpers ----------

__device__ __forceinline__ float rl(float v, int i) {
    return __builtin_bit_cast(float, __builtin_amdgcn_readlane(__builtin_bit_cast(int, v), i));
}
__device__ __forceinline__ float rfl(float v) {
    return __builtin_bit_cast(float, __builtin_amdgcn_readfirstlane(__builtin_bit_cast(int, v)));
}
__device__ __forceinline__ float wsum(float v) {
#pragma unroll
    for (int k = 32; k >= 1; k >>= 1) v += __shfl_xor(v, k, 64);
    return v;
}

// lane c owns column c of trans; E[i] = exp(trans[i][c] - s_c), s_c = max_i trans[i][c]
__device__ __forceinline__ float init_E(const float* s_trans, int c, float* E) {
    float sj = -1e30f;
#pragma unroll
    for (int i = 0; i < NN; ++i) sj = fmaxf(sj, s_trans[i * NN + c]);
#pragma unroll
    for (int i = 0; i < NN; ++i) E[i] = __expf(s_trans[i * NN + c] - sj);
    return sj;
}

// one CRF forward step: alpha'_j = s_j + log(sum_i exp(alpha_i - delta) E_ij) + em_j ; C += delta
__device__ __forceinline__ void crf_step(float& d, float& C, float em,
                                         const float* __restrict__ E, float sj) {
    float delta = rfl(d);
    float u = __expf(d - delta);
    float a0 = 0.f, a1 = 0.f, a2 = 0.f, a3 = 0.f;
#pragma unroll
    for (int i = 0; i < NN; i += 4) {
        a0 = fmaf(rl(u, i + 0), E[i + 0], a0);
        a1 = fmaf(rl(u, i + 1), E[i + 1], a1);
        a2 = fmaf(rl(u, i + 2), E[i + 2], a2);
        a3 = fmaf(rl(u, i + 3), E[i + 3], a3);
    }
    float v = (a0 + a1) + (a2 + a3);
    d = sj + __logf(v) + em;
    C += delta;
}

__device__ __forceinline__ float finish_logden(float d, float C, int lane) {
    float delta = rfl(d);
    float ex = (lane < NN) ? __expf(d - delta) : 0.f;
    float S = wsum(ex);
    return C + delta + __logf(S);
}

// ---------- kernels ----------

__global__ void zero_out(float* out) {
    if (threadIdx.x < 3) out[threadIdx.x] = 0.f;
}

// Fused kernel. Block roles:
//   bid 0..255          : T direction (1024 long sequences, 4 waves/block, 1 seq/wave)
//   bid 256.. (even r)  : L direction (8192 waves total, 4 seqs/wave)
//   bid 256.. (odd  r)  : R direction (same shape)
// T blocks go first so the long serial chains start immediately; L/R waves
// co-resident on the same SIMDs fill T's dependency-stall cycles.
__global__ __launch_bounds__(256) void crf_all(const float* __restrict__ logits,
                                               const float* __restrict__ transT,
                                               const float* __restrict__ transL,
                                               const float* __restrict__ transR,
                                               const int* __restrict__ tags,
                                               float* __restrict__ out) {
    __shared__ float s_trans[NN * NN];
    __shared__ float s_acc;
    int tid = threadIdx.x;
    int bid = blockIdx.x;

    int role;  // 0=T, 1=L, 2=R
    const float* tr;
    if (bid < 256) {
        role = 0; tr = transT;
    } else {
        int r = bid - 256;
        role = (r & 1) ? 2 : 1;
        tr = (r & 1) ? transR : transL;
    }
    if (tid == 0) s_acc = 0.f;
    for (int i = tid; i < NN * NN; i += 256) s_trans[i] = tr[i];
    __syncthreads();

    int lane = tid & 63, widx = tid >> 6;
    int c = (lane < NN) ? lane : (NN - 1);
    float E[NN];
    float sj = init_E(s_trans, c, E);

    const int SP = BB * TT;        // p-stride in tags
    const int SPN = BB * TT * NN;  // p-stride in logits

    if (role == 0) {
        // ---- T direction: one wave per (p,b) sequence, length TT-p ----
        int s = bid * 4 + widx;  // 0..1023 == p*64+b
        int p = s >> 6;
        int L = TT - p;
        const float* lg = logits + (size_t)s * TT * NN;
        float d = lg[c];
        float C = 0.f;
        float em_next = lg[NN + c];
        for (int t = 1; t < L; ++t) {
            float em = em_next;
            em_next = lg[(size_t)(t + 1) * NN + c];  // prefetch (stays inside logits buffer)
            crf_step(d, C, em, E, sj);
        }
        float log_den = finish_logden(d, C, lane);

        const int* tg = tags + (size_t)s * TT;
        float sc = 0.f;
        for (int t0 = 0; t0 < L; t0 += 64) {
            int t = t0 + lane;
            if (t < L) {
                int tag = tg[t];
                sc += lg[(size_t)t * NN + tag];
                if (t >= 1) sc += s_trans[tg[t - 1] * NN + tag];
            }
        }
        sc = wsum(sc);
        if (lane == 0) atomicAdd(&s_acc, log_den - sc);
    } else {
        // ---- L/R directions: 4 sequences per wave ----
        // L: element p at logits[p,b,t]   -> estride = SPN,      Lh = min(TT-t, 16), tstride = SP
        // R: element p at logits[p,b,t-p] -> estride = SPN - NN, Lh = min(t+1, 16),  tstride = SP-1
        int wgid = ((bid - 256) >> 1) * 4 + widx;  // 0..8191
        int estride = (role == 1) ? SPN : (SPN - NN);
        int tstride = (role == 1) ? SP : (SP - 1);

        float tot = 0.f;
#pragma unroll
        for (int k = 0; k < 4; ++k) {
            int sq = wgid + k * 8192;  // 0..32767 == t*64+b
            int t = sq >> 6, b = sq & 63;
            int Lh = (role == 1) ? min(TT - t, PP) : min(t + 1, PP);
            const float* base = logits + (size_t)(b * TT + t) * NN;
            float d = base[c];
            float C = 0.f;
            for (int ps = 1; ps < Lh; ++ps) {
                float em = base[(size_t)ps * estride + c];
                crf_step(d, C, em, E, sj);
            }
            float log_den = finish_logden(d, C, lane);

            float sc = 0.f;
            int tagv = 0;
            if (lane < Lh) tagv = tags[lane * tstride + b * TT + t];
            int tprev = __shfl_up(tagv, 1, 64);
            if (lane < Lh) {
                sc += base[(size_t)lane * estride + tagv];
                if (lane >= 1) sc += s_trans[tprev * NN + tagv];
            }
            sc = wsum(sc);
            if (lane == 0) tot += log_den - sc;
        }
        if (lane == 0) atomicAdd(&s_acc, tot);
    }

    __syncthreads();
    if (tid == 0) atomicAdd(&out[role], s_acc);
}

// ---------- launch ----------

extern "C" void kernel_launch(void* const* d_in, const int* in_sizes, int n_in,
                              void* d_out, int out_size, void* d_ws, size_t ws_size,
                              hipStream_t stream) {
    const float* logits = (const float*)d_in[0];
    const float* trans_T = (const float*)d_in[1];
    const float* trans_L = (const float*)d_in[2];
    const float* trans_R = (const float*)d_in[3];
    const int* tags = (const int*)d_in[4];
    float* out = (float*)d_out;

    hipLaunchKernelGGL(zero_out, dim3(1), dim3(64), 0, stream, out);
    hipLaunchKernelGGL(crf_all, dim3(256 + 4096), dim3(256), 0, stream,
                       logits, trans_T, trans_L, trans_R, tags, out);
}